// Round 1
// baseline (4300.029 us; speedup 1.0000x reference)
//
#include <hip/hip_runtime.h>
#include <cstdint>
#include <cstddef>

#define B_ 64
#define T_ 512
#define I_ 256
#define H_ 1024
#define O_ 128

typedef __attribute__((ext_vector_type(8))) short short8;   // 8 x bf16 frag
typedef __attribute__((ext_vector_type(4))) float f32x4;    // MFMA accumulator

__device__ __forceinline__ short f2bf(float f) {
    union { float f; unsigned int u; } v; v.f = f;
    unsigned int r = v.u + 0x7fffu + ((v.u >> 16) & 1u);   // RNE
    return (short)(r >> 16);
}
__device__ __forceinline__ float bf2f(unsigned short h) {
    union { float f; unsigned int u; } v; v.u = ((unsigned int)h) << 16;
    return v.f;
}
__device__ __forceinline__ short8 pack8(const float* p) {
    float4 a = *(const float4*)p;
    float4 b = *(const float4*)(p + 4);
    short8 r;
    r[0] = f2bf(a.x); r[1] = f2bf(a.y); r[2] = f2bf(a.z); r[3] = f2bf(a.w);
    r[4] = f2bf(b.x); r[5] = f2bf(b.y); r[6] = f2bf(b.z); r[7] = f2bf(b.w);
    return r;
}
__device__ __forceinline__ f32x4 zero4() {
    f32x4 v; v[0] = 0.f; v[1] = 0.f; v[2] = 0.f; v[3] = 0.f; return v;
}

// ---------------------------------------------------------------------------
// Phase A: xp[t][b][h] = sum_i x[b][t][i] * W_ih[h][i] + b_ih[h] + b_hh[h]
// GEMM M=B*T (tile: 64 rows = all b for one t), N=H (tile 64), K=I=256.
// 4 waves per WG, each wave a 32x32 sub-tile (2x2 MFMA 16x16x32 frags).
// Operands loaded straight from global (L2-resident), converted fp32->bf16.
// ---------------------------------------------------------------------------
__global__ __launch_bounds__(256) void xproj_kernel(
        const float* __restrict__ x, const float* __restrict__ W_ih,
        const float* __restrict__ b_ih, const float* __restrict__ b_hh,
        unsigned short* __restrict__ xp) {
    const int t     = blockIdx.x;        // 0..511
    const int ntile = blockIdx.y;        // 0..15
    const int tid   = threadIdx.x;
    const int wave  = tid >> 6, lane = tid & 63;
    const int m     = lane & 15, quad = lane >> 4;
    const int wrow  = (wave & 1) * 32;   // row offset inside 64-row tile
    const int wcol  = (wave >> 1) * 32;  // col offset inside 64-col tile

    f32x4 acc[2][2];
    for (int i = 0; i < 2; ++i)
        for (int j = 0; j < 2; ++j) acc[i][j] = zero4();

    #pragma unroll
    for (int ks = 0; ks < 8; ++ks) {           // K = 256 = 8 * 32
        const int kb = ks * 32 + quad * 8;
        short8 af[2], bfr[2];
        #pragma unroll
        for (int rt = 0; rt < 2; ++rt) {
            const int bl = wrow + rt * 16 + m; // batch row (A-frag row)
            af[rt] = pack8(x + ((size_t)bl * T_ + t) * I_ + kb);
        }
        #pragma unroll
        for (int ct = 0; ct < 2; ++ct) {
            const int col = ntile * 64 + wcol + ct * 16 + m;
            bfr[ct] = pack8(W_ih + (size_t)col * I_ + kb);
        }
        #pragma unroll
        for (int rt = 0; rt < 2; ++rt)
            #pragma unroll
            for (int ct = 0; ct < 2; ++ct)
                acc[rt][ct] = __builtin_amdgcn_mfma_f32_16x16x32_bf16(
                    af[rt], bfr[ct], acc[rt][ct], 0, 0, 0);
    }

    // Epilogue: C/D layout col=lane&15, row=quad*4+reg (m89/m91 verified)
    #pragma unroll
    for (int ct = 0; ct < 2; ++ct) {
        const int col = ntile * 64 + wcol + ct * 16 + m;
        const float bias = b_ih[col] + b_hh[col];
        #pragma unroll
        for (int rt = 0; rt < 2; ++rt) {
            #pragma unroll
            for (int r = 0; r < 4; ++r) {
                const int bl = wrow + rt * 16 + quad * 4 + r;
                xp[((size_t)t * B_ + bl) * H_ + col] =
                    (unsigned short)f2bf(acc[rt][ct][r] + bias);
            }
        }
    }
}

// ---------------------------------------------------------------------------
// Phase B: persistent recurrence kernel.
// 64 WGs = 4 batch-groups (16 rows) x 16 column-slices (64 cols).
// Each wave owns 16 output columns; its W_hh slice lives in 128 VGPRs of
// pre-packed B-fragments for the whole kernel. Per step: stage group h-slice
// (16x1024 bf16) to LDS, 32 MFMAs (2 acc chains), +xp, tanh, write ping-pong,
// then a 16-WG agent-scope barrier (monotonic counter, no reinit).
// ---------------------------------------------------------------------------
#define LDS_STRIDE 1032   // 1024 + 8 bf16 pad: b128 start banks spread evenly

__global__ __launch_bounds__(256, 1) void rnn_kernel(
        const float* __restrict__ W_hh, const unsigned short* __restrict__ xp,
        unsigned short* __restrict__ hbuf, unsigned int* __restrict__ barrier_ctr) {
    const int group = blockIdx.x >> 4;   // 0..3  (16 batch rows each)
    const int slice = blockIdx.x & 15;   // 0..15 (64 H-cols each)
    const int tid   = threadIdx.x;
    const int wave  = tid >> 6, lane = tid & 63;
    const int m     = lane & 15, quad = lane >> 4;
    const int col   = slice * 64 + wave * 16 + m;   // this lane's B column

    __shared__ unsigned short lds_h[16 * LDS_STRIDE];

    // Preload W_hh B-frags: b_frag[j] = W_hh[col][ks*32 + quad*8 + j]
    short8 bfrag[32];
    #pragma unroll
    for (int ks = 0; ks < 32; ++ks)
        bfrag[ks] = pack8(W_hh + (size_t)col * H_ + ks * 32 + quad * 8);

    unsigned int* ctr = barrier_ctr + group * 32;   // 128B-separated counters
    const int srow = tid & 15, sseg = tid >> 4;     // staging: (row, 16B-seg)

    for (int t = 0; t < T_; ++t) {
        const unsigned short* hsrc = hbuf + (size_t)(t & 1) * (B_ * H_)
                                          + (size_t)group * 16 * H_;
        unsigned short* hdst = hbuf + (size_t)((t + 1) & 1) * (B_ * H_);

        // stage 16x1024 bf16 (32 KB) into padded LDS
        #pragma unroll
        for (int it = 0; it < 8; ++it) {
            const int seg16 = it * 16 + sseg;       // 0..127 (16B units)
            uint4 v = *(const uint4*)(hsrc + (size_t)srow * H_ + seg16 * 8);
            *(uint4*)(&lds_h[srow * LDS_STRIDE + seg16 * 8]) = v;
        }
        __syncthreads();

        // K loop: A-frag A[m=lane&15][k=quad*8+j] from LDS, B from registers
        f32x4 acc0 = zero4(), acc1 = zero4();
        #pragma unroll
        for (int ks = 0; ks < 32; ks += 2) {
            short8 a0 = *(const short8*)(&lds_h[m * LDS_STRIDE + ks * 32 + quad * 8]);
            short8 a1 = *(const short8*)(&lds_h[m * LDS_STRIDE + (ks + 1) * 32 + quad * 8]);
            acc0 = __builtin_amdgcn_mfma_f32_16x16x32_bf16(a0, bfrag[ks],     acc0, 0, 0, 0);
            acc1 = __builtin_amdgcn_mfma_f32_16x16x32_bf16(a1, bfrag[ks + 1], acc1, 0, 0, 0);
        }

        // epilogue: +xp, tanh, store bf16 h
        #pragma unroll
        for (int r = 0; r < 4; ++r) {
            const int bg = group * 16 + quad * 4 + r;   // C row = batch row
            float v = acc0[r] + acc1[r]
                    + bf2f(xp[((size_t)t * B_ + bg) * H_ + col]);
            v = tanhf(v);
            hdst[(size_t)bg * H_ + col] = (unsigned short)f2bf(v);
        }
        __syncthreads();   // LDS safe to restage; all stores issued+drained

        if (t < T_ - 1) {
            if (tid == 0) {
                __threadfence();   // agent release: L2 writeback (cross-XCD)
                __hip_atomic_fetch_add(ctr, 1u, __ATOMIC_ACQ_REL,
                                       __HIP_MEMORY_SCOPE_AGENT);
                const unsigned int target = 16u * (unsigned int)(t + 1);
                while (__hip_atomic_load(ctr, __ATOMIC_ACQUIRE,
                                         __HIP_MEMORY_SCOPE_AGENT) < target)
                    __builtin_amdgcn_s_sleep(1);
                __threadfence();   // agent acquire: invalidate stale L1/L2
            }
            __syncthreads();
        }
    }
}

// ---------------------------------------------------------------------------
// Phase C: out[b][o] = h_final[b][:] . W_lin[o][:] + b_lin[o]; one wave/output
// ---------------------------------------------------------------------------
__global__ __launch_bounds__(256) void out_kernel(
        const unsigned short* __restrict__ hfinal, const float* __restrict__ W_lin,
        const float* __restrict__ b_lin, float* __restrict__ out) {
    const int gwave = (int)((blockIdx.x * 256 + threadIdx.x) >> 6);  // 0..8191
    const int lane  = threadIdx.x & 63;
    const int b = gwave >> 7, o = gwave & 127;

    const unsigned short* hp = hfinal + (size_t)b * H_ + lane * 16;
    const float*          wp = W_lin  + (size_t)o * H_ + lane * 16;
    float s = 0.f;
    #pragma unroll
    for (int j = 0; j < 16; ++j) s += bf2f(hp[j]) * wp[j];
    #pragma unroll
    for (int d = 32; d > 0; d >>= 1) s += __shfl_down(s, d, 64);
    if (lane == 0) out[(size_t)b * O_ + o] = s + b_lin[o];
}

// ---------------------------------------------------------------------------
extern "C" void kernel_launch(void* const* d_in, const int* in_sizes, int n_in,
                              void* d_out, int out_size, void* d_ws, size_t ws_size,
                              hipStream_t stream) {
    const float* x     = (const float*)d_in[0];
    const float* W_ih  = (const float*)d_in[1];
    const float* W_hh  = (const float*)d_in[2];
    const float* b_ih  = (const float*)d_in[3];
    const float* b_hh  = (const float*)d_in[4];
    const float* W_lin = (const float*)d_in[5];
    const float* b_lin = (const float*)d_in[6];

    const size_t XP_ELEMS = (size_t)T_ * B_ * H_;        // 33.5M bf16 = 64 MB
    unsigned short* xp   = (unsigned short*)d_ws;
    unsigned short* hbuf = xp + XP_ELEMS;                // 2 x (64*1024) bf16
    unsigned int*   ctr  = (unsigned int*)(hbuf + 2 * (size_t)B_ * H_);

    // zero h0 (+h1) and barrier counters (ws is re-poisoned 0xAA every launch)
    hipMemsetAsync(hbuf, 0,
                   2 * (size_t)B_ * H_ * sizeof(unsigned short)
                   + 4 * 32 * sizeof(unsigned int), stream);

    dim3 gA(T_, H_ / 64);
    xproj_kernel<<<gA, 256, 0, stream>>>(x, W_ih, b_ih, b_hh, xp);
    rnn_kernel<<<64, 256, 0, stream>>>(W_hh, xp, hbuf, ctr);
    out_kernel<<<(B_ * O_) / 4, 256, 0, stream>>>(hbuf, W_lin, b_lin, (float*)d_out);
}

// Round 2
// 2643.602 us; speedup vs baseline: 1.6266x; 1.6266x over previous
//
#include <hip/hip_runtime.h>
#include <cstdint>
#include <cstddef>

#define B_ 64
#define T_ 512
#define I_ 256
#define H_ 1024
#define O_ 128

typedef __attribute__((ext_vector_type(8))) short short8;   // 8 x bf16 frag
typedef __attribute__((ext_vector_type(4))) float f32x4;    // MFMA accumulator

__device__ __forceinline__ unsigned short f2bf(float f) {
    union { float f; unsigned int u; } v; v.f = f;
    unsigned int r = v.u + 0x7fffu + ((v.u >> 16) & 1u);   // RNE
    return (unsigned short)(r >> 16);
}
__device__ __forceinline__ float bf2f(unsigned short h) {
    union { float f; unsigned int u; } v; v.u = ((unsigned int)h) << 16;
    return v.f;
}
__device__ __forceinline__ short8 pack8(const float* p) {
    float4 a = *(const float4*)p;
    float4 b = *(const float4*)(p + 4);
    short8 r;
    r[0] = (short)f2bf(a.x); r[1] = (short)f2bf(a.y);
    r[2] = (short)f2bf(a.z); r[3] = (short)f2bf(a.w);
    r[4] = (short)f2bf(b.x); r[5] = (short)f2bf(b.y);
    r[6] = (short)f2bf(b.z); r[7] = (short)f2bf(b.w);
    return r;
}
__device__ __forceinline__ f32x4 zero4() {
    f32x4 v; v[0] = 0.f; v[1] = 0.f; v[2] = 0.f; v[3] = 0.f; return v;
}

// ---------------------------------------------------------------------------
// Phase A: xp[t][b][h] = sum_i x[b][t][i] * W_ih[h][i] + b_ih[h] + b_hh[h]
// Grid (16, 512): blockIdx.x = ntile (fast axis -> 16 same-t WGs concurrent,
// sharing the x[t] slice through L2), blockIdx.y = t.
// x[t] (64 rows x 256) staged once into LDS as bf16 via coalesced float4.
// ---------------------------------------------------------------------------
#define XS 264   // LDS row stride (shorts): 528 B, 16B-aligned

__global__ __launch_bounds__(256) void xproj_kernel(
        const float* __restrict__ x, const float* __restrict__ W_ih,
        const float* __restrict__ b_ih, const float* __restrict__ b_hh,
        unsigned short* __restrict__ xp) {
    const int ntile = blockIdx.x;        // 0..15
    const int t     = blockIdx.y;        // 0..511
    const int tid   = threadIdx.x;
    const int wave  = tid >> 6, lane = tid & 63;
    const int m     = lane & 15, quad = lane >> 4;
    const int wrow  = (wave & 1) * 32;   // row offset inside 64-row tile
    const int wcol  = (wave >> 1) * 32;  // col offset inside 64-col tile

    __shared__ unsigned short lds_x[64 * XS];

    // stage x[:, t, :] -> bf16 LDS. 4 threads/row, 64 floats each.
    {
        const int row = tid >> 2, c = tid & 3;
        const float* xrow = x + ((size_t)row * T_ + t) * I_ + c * 64;
        #pragma unroll
        for (int j = 0; j < 16; ++j) {
            float4 v = *(const float4*)(xrow + j * 4);
            uint2 p;
            p.x = (unsigned)f2bf(v.x) | ((unsigned)f2bf(v.y) << 16);
            p.y = (unsigned)f2bf(v.z) | ((unsigned)f2bf(v.w) << 16);
            *(uint2*)(&lds_x[row * XS + c * 64 + j * 4]) = p;
        }
    }
    __syncthreads();

    f32x4 acc[2][2];
    for (int i = 0; i < 2; ++i)
        for (int j = 0; j < 2; ++j) acc[i][j] = zero4();

    #pragma unroll
    for (int ks = 0; ks < 8; ++ks) {           // K = 256 = 8 * 32
        const int kb = ks * 32 + quad * 8;
        short8 af[2], bfr[2];
        #pragma unroll
        for (int rt = 0; rt < 2; ++rt) {
            const int bl = wrow + rt * 16 + m; // batch row (A-frag row)
            af[rt] = *(const short8*)(&lds_x[bl * XS + kb]);
        }
        #pragma unroll
        for (int ct = 0; ct < 2; ++ct) {
            const int col = ntile * 64 + wcol + ct * 16 + m;
            bfr[ct] = pack8(W_ih + (size_t)col * I_ + kb);
        }
        #pragma unroll
        for (int rt = 0; rt < 2; ++rt)
            #pragma unroll
            for (int ct = 0; ct < 2; ++ct)
                acc[rt][ct] = __builtin_amdgcn_mfma_f32_16x16x32_bf16(
                    af[rt], bfr[ct], acc[rt][ct], 0, 0, 0);
    }

    // Epilogue: C/D layout col=lane&15, row=quad*4+reg (m89/m91 verified)
    #pragma unroll
    for (int ct = 0; ct < 2; ++ct) {
        const int col = ntile * 64 + wcol + ct * 16 + m;
        const float bias = b_ih[col] + b_hh[col];
        #pragma unroll
        for (int rt = 0; rt < 2; ++rt) {
            #pragma unroll
            for (int r = 0; r < 4; ++r) {
                const int bl = wrow + rt * 16 + quad * 4 + r;
                xp[((size_t)t * B_ + bl) * H_ + col] =
                    (unsigned short)f2bf(acc[rt][ct][r] + bias);
            }
        }
    }
}

// ---------------------------------------------------------------------------
// Phase B: persistent recurrence kernel.
// 64 WGs = 4 batch-groups (16 rows) x 16 column-slices (64 cols).
// W_hh slice lives in 128 VGPRs/lane of pre-packed B-frags for the whole
// kernel. Per step: stage group h-slice (16x1024 bf16) to LDS, 32 MFMAs,
// +xp, tanh, write h ping-pong, then a 16-WG monotonic-counter barrier:
//   release fetch_add (one wbl2) -> RELAXED polls (coherent sc0/sc1 load,
//   NO buffer_inv per poll) -> single ACQUIRE load (one buffer_inv).
// ---------------------------------------------------------------------------
#define LDS_STRIDE 1032   // 1024 + 8 bf16 pad; 16B-aligned rows

__global__ __launch_bounds__(256, 1) void rnn_kernel(
        const float* __restrict__ W_hh, const unsigned short* __restrict__ xp,
        unsigned short* __restrict__ hbuf, unsigned int* __restrict__ barrier_ctr) {
    const int group = blockIdx.x >> 4;   // 0..3  (16 batch rows each)
    const int slice = blockIdx.x & 15;   // 0..15 (64 H-cols each)
    const int tid   = threadIdx.x;
    const int wave  = tid >> 6, lane = tid & 63;
    const int m     = lane & 15, quad = lane >> 4;
    const int col   = slice * 64 + wave * 16 + m;   // this lane's B column

    __shared__ unsigned short lds_h[16 * LDS_STRIDE];

    // Preload W_hh B-frags: b_frag[j] = W_hh[col][ks*32 + quad*8 + j]
    short8 bfrag[32];
    #pragma unroll
    for (int ks = 0; ks < 32; ++ks)
        bfrag[ks] = pack8(W_hh + (size_t)col * H_ + ks * 32 + quad * 8);

    unsigned int* ctr = barrier_ctr + group * 32;   // 128B-separated counters
    const int srow = tid & 15, sseg = tid >> 4;     // staging: (row, 16B-seg)

    for (int t = 0; t < T_; ++t) {
        const unsigned short* hsrc = hbuf + (size_t)(t & 1) * (B_ * H_)
                                          + (size_t)group * 16 * H_;
        unsigned short* hdst = hbuf + (size_t)((t + 1) & 1) * (B_ * H_);

        // prefetch this step's xp values (independent of h) so the loads
        // overlap LDS staging + MFMA
        unsigned short xpv[4];
        {
            const unsigned short* xpp =
                xp + ((size_t)t * B_ + group * 16 + quad * 4) * H_ + col;
            #pragma unroll
            for (int r = 0; r < 4; ++r) xpv[r] = xpp[(size_t)r * H_];
        }

        // stage 16x1024 bf16 (32 KB) into padded LDS
        #pragma unroll
        for (int it = 0; it < 8; ++it) {
            const int seg16 = it * 16 + sseg;       // 0..127 (16B units)
            uint4 v = *(const uint4*)(hsrc + (size_t)srow * H_ + seg16 * 8);
            *(uint4*)(&lds_h[srow * LDS_STRIDE + seg16 * 8]) = v;
        }
        __syncthreads();

        // K loop: A-frag A[m=lane&15][k=quad*8+j] from LDS, B from registers
        f32x4 acc0 = zero4(), acc1 = zero4();
        #pragma unroll
        for (int ks = 0; ks < 32; ks += 2) {
            short8 a0 = *(const short8*)(&lds_h[m * LDS_STRIDE + ks * 32 + quad * 8]);
            short8 a1 = *(const short8*)(&lds_h[m * LDS_STRIDE + (ks + 1) * 32 + quad * 8]);
            acc0 = __builtin_amdgcn_mfma_f32_16x16x32_bf16(a0, bfrag[ks],     acc0, 0, 0, 0);
            acc1 = __builtin_amdgcn_mfma_f32_16x16x32_bf16(a1, bfrag[ks + 1], acc1, 0, 0, 0);
        }

        // epilogue: +xp, tanh, store bf16 h
        #pragma unroll
        for (int r = 0; r < 4; ++r) {
            const int bg = group * 16 + quad * 4 + r;   // C row = batch row
            float v = acc0[r] + acc1[r] + bf2f(xpv[r]);
            v = tanhf(v);
            hdst[(size_t)bg * H_ + col] = (unsigned short)f2bf(v);
        }
        __syncthreads();   // drains all waves' stores to L2; LDS restage safe

        if (t < T_ - 1) {
            if (tid == 0) {
                // release: one waitcnt + one wbl2 (covers whole WG's stores,
                // all on this CU/XCD), then the coherent RMW at IF$
                __hip_atomic_fetch_add(ctr, 1u, __ATOMIC_RELEASE,
                                       __HIP_MEMORY_SCOPE_AGENT);
                const unsigned int target = 16u * (unsigned int)(t + 1);
                // relaxed polls: coherent (bypass L1/L2) but NO cache inv
                while (__hip_atomic_load(ctr, __ATOMIC_RELAXED,
                                         __HIP_MEMORY_SCOPE_AGENT) < target) {}
                // exactly one acquire (single buffer_inv for this CU/XCD)
                __hip_atomic_load(ctr, __ATOMIC_ACQUIRE,
                                  __HIP_MEMORY_SCOPE_AGENT);
            }
            __syncthreads();
        }
    }
}

// ---------------------------------------------------------------------------
// Phase C: out[b][o] = h_final[b][:] . W_lin[o][:] + b_lin[o]; one wave/output
// ---------------------------------------------------------------------------
__global__ __launch_bounds__(256) void out_kernel(
        const unsigned short* __restrict__ hfinal, const float* __restrict__ W_lin,
        const float* __restrict__ b_lin, float* __restrict__ out) {
    const int gwave = (int)((blockIdx.x * 256 + threadIdx.x) >> 6);  // 0..8191
    const int lane  = threadIdx.x & 63;
    const int b = gwave >> 7, o = gwave & 127;

    const unsigned short* hp = hfinal + (size_t)b * H_ + lane * 16;
    const float*          wp = W_lin  + (size_t)o * H_ + lane * 16;
    float s = 0.f;
    #pragma unroll
    for (int j = 0; j < 16; ++j) s += bf2f(hp[j]) * wp[j];
    #pragma unroll
    for (int d = 32; d > 0; d >>= 1) s += __shfl_down(s, d, 64);
    if (lane == 0) out[(size_t)b * O_ + o] = s + b_lin[o];
}

// ---------------------------------------------------------------------------
extern "C" void kernel_launch(void* const* d_in, const int* in_sizes, int n_in,
                              void* d_out, int out_size, void* d_ws, size_t ws_size,
                              hipStream_t stream) {
    const float* x     = (const float*)d_in[0];
    const float* W_ih  = (const float*)d_in[1];
    const float* W_hh  = (const float*)d_in[2];
    const float* b_ih  = (const float*)d_in[3];
    const float* b_hh  = (const float*)d_in[4];
    const float* W_lin = (const float*)d_in[5];
    const float* b_lin = (const float*)d_in[6];

    const size_t XP_ELEMS = (size_t)T_ * B_ * H_;        // 33.5M bf16 = 64 MB
    unsigned short* xp   = (unsigned short*)d_ws;
    unsigned short* hbuf = xp + XP_ELEMS;                // 2 x (64*1024) bf16
    unsigned int*   ctr  = (unsigned int*)(hbuf + 2 * (size_t)B_ * H_);

    // zero h0 (+h1) and barrier counters (ws is re-poisoned 0xAA every launch)
    hipMemsetAsync(hbuf, 0,
                   2 * (size_t)B_ * H_ * sizeof(unsigned short)
                   + 4 * 32 * sizeof(unsigned int), stream);

    dim3 gA(H_ / 64, T_);    // ntile fast axis: same-t WGs share x via L2
    xproj_kernel<<<gA, 256, 0, stream>>>(x, W_ih, b_ih, b_hh, xp);
    rnn_kernel<<<64, 256, 0, stream>>>(W_hh, xp, hbuf, ctr);
    out_kernel<<<(B_ * O_) / 4, 256, 0, stream>>>(hbuf, W_lin, b_lin, (float*)d_out);
}